// Round 17
// baseline (130.725 us; speedup 1.0000x reference)
//
#include <hip/hip_runtime.h>
#include <cstddef>

#define IMG 256
#define HW 65536
#define NB 4
#define NHEADS 8
#define TW 32
#define TH 8
#define HAW 34
#define HAH 10
#define HP2 (HAW*HAH)   // 340
#define NTILE 256       // (256/32)*(256/8)
#define XSP 56          // xs pitch in ushorts (112 B, 16B-aligned)

typedef short bf16x8 __attribute__((ext_vector_type(8)));
typedef float f32x4 __attribute__((ext_vector_type(4)));
typedef float f32x16 __attribute__((ext_vector_type(16)));

__device__ __forceinline__ unsigned short f2bf(float f) {
    unsigned int x = __float_as_uint(f);
    unsigned int r = (x + 0x7fffu + ((x >> 16) & 1u)) >> 16;
    return (unsigned short)r;
}

// bijective XCD-contiguous remap (m204)
__device__ __forceinline__ int xcd_map(int bid, int nwg) {
    const int q = nwg >> 3, r = nwg & 7;
    const int x = bid & 7, i = bid >> 3;
    return (x < r ? x * (q + 1) : r * (q + 1) + (x - r) * q) + i;
}

// ---------------------------------------------------------------------------
// K0: combined qk 3x3 weights, layout [tap][slot128][48ch]
// ---------------------------------------------------------------------------
__global__ __launch_bounds__(256) void prep_qcw_kernel(
    const float* __restrict__ qk_w, const float* __restrict__ qk_dw,
    unsigned short* __restrict__ qcwb) {
    const int idx = blockIdx.x * 256 + threadIdx.x;   // 9*128*48 = 55296 exact
    const int e = idx % 48;
    const int slot = (idx / 48) & 127;
    const int tap = idx / (48 * 128);
    const int head = slot >> 4, sub = slot & 15;
    float v = 0.f;
    if (sub < 12) {
        const int row = (sub < 6) ? (head * 6 + sub) : (48 + head * 6 + (sub - 6));
        v = qk_dw[row * 9 + tap] * qk_w[row * 48 + e];
    }
    qcwb[idx] = f2bf(v);
}

// ---------------------------------------------------------------------------
// K1: qk conv + stats. 32x8 tile, 512 thr (8 waves = mp(4) x g(2)).
//  R13 structure (measured best: 52.5 us). Registers cap occupancy at 4
//  waves/SIMD (64 arch + 64 AGPR = 128 unified); LDS/block-size variants
//  (R14/R15) don't move it. setprio(1) around the MFMA tap loop: no barriers
//  inside the ks loop -> waves drift out of phase -> MFMA-phase waves win
//  CU arbitration (T5 regime).
// stats per b (384 f32): [0..47]=qq(h*6+c), [48..95]=kk, [96..]=h*36+cc*6+d
// LDS: 38080 + 18432 + 1536 = 58048 B
// ---------------------------------------------------------------------------
__global__ __launch_bounds__(512, 2) void fused_qk_stats_kernel(
    const float* __restrict__ fea0, const unsigned short* __restrict__ qcwb,
    float* __restrict__ stats) {
    __shared__ __align__(16) unsigned short xs[HP2][XSP];   // 38080 B
    __shared__ __align__(16) unsigned short sg[8][16][72];  // 18432 B
    __shared__ float sacc[384];

    const int tid = threadIdx.x;
    const int b = blockIdx.y;
    const int tile = xcd_map(blockIdx.x, NTILE);
    const int tx = tile & 7, ty = tile >> 3;
    const float* fb = fea0 + (size_t)b * 48 * HW;

    for (int i = tid; i < 384; i += 512) sacc[i] = 0.f;

    // ---- stage 34x10 halo, 48 ch, bf16 (2 threads per px) ----
#pragma unroll 1
    for (int i = tid; i < 2 * HP2; i += 512) {
        const int hp = i >> 1, half = i & 1;
        const int hx = hp % HAW, hy = hp / HAW;
        const int gx = tx * TW + hx - 1, gy = ty * TH + hy - 1;
        const bool inb = ((unsigned)gx < (unsigned)IMG) && ((unsigned)gy < (unsigned)IMG);
        const int pix = inb ? (gy * IMG + gx) : 0;
        const int ch0 = half * 24;
        unsigned int w[12];
#pragma unroll
        for (int c = 0; c < 12; ++c) {
            const float lo = inb ? fb[(size_t)(ch0 + 2 * c) * HW + pix] : 0.f;
            const float hi = inb ? fb[(size_t)(ch0 + 2 * c + 1) * HW + pix] : 0.f;
            w[c] = (unsigned)f2bf(lo) | ((unsigned)f2bf(hi) << 16);
        }
#pragma unroll
        for (int c = 0; c < 12; ++c)
            *(unsigned int*)&xs[hp][ch0 + 2 * c] = w[c];
    }
    __syncthreads();

    const int wave = tid >> 6, lane = tid & 63;
    const int l31 = lane & 31, lhi = lane >> 5;
    const int mp = wave >> 1, g = wave & 1;

    f32x16 C[4];
#pragma unroll
    for (int nf = 0; nf < 4; ++nf)
#pragma unroll
        for (int r = 0; r < 16; ++r) C[nf][r] = 0.f;

#pragma unroll 1
    for (int ks = 0; ks < 3; ++ks) {
        // 18 deduped B fragments: halo rows 4g..4g+5, dx shifts 0..2
        bf16x8 Bc[6][3];
#pragma unroll
        for (int rr = 0; rr < 6; ++rr)
#pragma unroll
            for (int dd = 0; dd < 3; ++dd)
                Bc[rr][dd] = *(const bf16x8*)&xs[(4 * g + rr) * HAW + l31 + dd][ks * 16 + lhi * 8];
        // 9 A fragments for this ks
        bf16x8 Af[9];
#pragma unroll
        for (int tap = 0; tap < 9; ++tap)
            Af[tap] = *(const bf16x8*)&qcwb[((size_t)tap * 128 + mp * 32 + l31) * 48 + ks * 16 + lhi * 8];
        __builtin_amdgcn_s_setprio(1);
#pragma unroll
        for (int tap = 0; tap < 9; ++tap) {
            const int dy = tap / 3, dx = tap % 3;
#pragma unroll
            for (int nf = 0; nf < 4; ++nf)
                C[nf] = __builtin_amdgcn_mfma_f32_32x32x16_bf16(Af[tap], Bc[nf + dy][dx], C[nf], 0, 0, 0);
        }
        __builtin_amdgcn_s_setprio(0);
    }

    // ---- stats: no barrier needed (sg[wave] is wave-private) ----
    const int fr = lane & 15, fg = lane >> 4;
    f32x4 gacc[2];
#pragma unroll
    for (int hh = 0; hh < 2; ++hh)
#pragma unroll
        for (int r = 0; r < 4; ++r) gacc[hh][r] = 0.f;

#pragma unroll
    for (int pair = 0; pair < 2; ++pair) {     // px groups: (C0,C1), (C2,C3)
#pragma unroll
        for (int hh = 0; hh < 2; ++hh) {       // head within mp-pair
#pragma unroll
            for (int rq = 0; rq < 2; ++rq) {
                if (!(rq && lhi)) {
#pragma unroll
                    for (int j = 0; j < 4; ++j) {
                        const int sub = j + 8 * rq + 4 * lhi;
                        sg[wave][sub][l31] = f2bf(C[pair * 2][hh * 8 + rq * 4 + j]);
                        sg[wave][sub][32 + l31] = f2bf(C[pair * 2 + 1][hh * 8 + rq * 4 + j]);
                    }
                }
            }
            asm volatile("s_waitcnt lgkmcnt(0)" ::: "memory");
            __builtin_amdgcn_sched_barrier(0);
            const bf16x8 a0 = *(const bf16x8*)&sg[wave][fr][fg * 8];
            const bf16x8 a1 = *(const bf16x8*)&sg[wave][fr][32 + fg * 8];
            asm volatile("s_waitcnt lgkmcnt(0)" ::: "memory");
            __builtin_amdgcn_sched_barrier(0);
            gacc[hh] = __builtin_amdgcn_mfma_f32_16x16x32_bf16(a0, a0, gacc[hh], 0, 0, 0);
            gacc[hh] = __builtin_amdgcn_mfma_f32_16x16x32_bf16(a1, a1, gacc[hh], 0, 0, 0);
        }
    }

    // ---- emit once per head ----
#pragma unroll
    for (int hh = 0; hh < 2; ++hh) {
        const int h = mp * 2 + hh;
#pragma unroll
        for (int r = 0; r < 4; ++r) {
            const int crow = fg * 4 + r;
            const float vv = gacc[hh][r];
            if (crow < 6) {
                if (fr == crow) atomicAdd(&sacc[h * 6 + crow], vv);
                else if (fr >= 6 && fr < 12)
                    atomicAdd(&sacc[96 + h * 36 + crow * 6 + (fr - 6)], vv);
            } else if (crow < 12 && fr == crow) {
                atomicAdd(&sacc[48 + h * 6 + (crow - 6)], vv);
            }
        }
    }

    __syncthreads();
    for (int i = tid; i < 384; i += 512) atomicAdd(&stats[b * 384 + i], sacc[i]);
}

// ---------------------------------------------------------------------------
// K2: softmax(6) -> W2 = proj . blockdiag(attn) -> combined v-side weights
//  cwb layout [tap][slot64][48] (slots 48..63 zero), bf16.
// ---------------------------------------------------------------------------
__global__ __launch_bounds__(256) void softmax_w2_cw_kernel(
    const float* __restrict__ stats, const float* __restrict__ proj_w,
    const float* __restrict__ temperature, const float* __restrict__ v_w,
    const float* __restrict__ v_dw, unsigned short* __restrict__ cwb) {
    const int b = blockIdx.x;
    const int tid = threadIdx.x;
    __shared__ float attn[NHEADS * 36];
    __shared__ float W2s[48 * 48];
    const float* sb = stats + b * 384;

    if (tid < 48) {
        const int h = tid / 6, cc = tid % 6;
        float nq = fmaxf(sqrtf(sb[tid]), 1e-12f);
        const float tmp = temperature[h];
        float lo[6];
#pragma unroll
        for (int d = 0; d < 6; ++d) {
            const float nk = fmaxf(sqrtf(sb[48 + h * 6 + d]), 1e-12f);
            lo[d] = sb[96 + h * 36 + cc * 6 + d] / (nq * nk) * tmp;
        }
        float m = lo[0];
#pragma unroll
        for (int d = 1; d < 6; ++d) m = fmaxf(m, lo[d]);
        float s = 0.f;
#pragma unroll
        for (int d = 0; d < 6; ++d) { lo[d] = expf(lo[d] - m); s += lo[d]; }
        const float inv = 1.f / s;
#pragma unroll
        for (int d = 0; d < 6; ++d) attn[h * 36 + cc * 6 + d] = lo[d] * inv;
    }
    __syncthreads();

    for (int idx = tid; idx < 48 * 48; idx += 256) {
        const int c = idx / 48, dg = idx % 48;
        const int h = dg / 6, hd = dg % 6;
        float s = 0.f;
#pragma unroll
        for (int cc = 0; cc < 6; ++cc)
            s = fmaf(proj_w[c * 48 + h * 6 + cc], attn[h * 36 + cc * 6 + hd], s);
        W2s[idx] = s;
    }
    __syncthreads();

    unsigned short* cb = cwb + (size_t)b * 27648;
    for (int pp = 0; pp < 9; ++pp) {
        const int pair = pp * 256 + tid;
        const int c = pair / 48, e = pair % 48;
        float acc[9];
#pragma unroll
        for (int t = 0; t < 9; ++t) acc[t] = 0.f;
        for (int d = 0; d < 48; ++d) {
            const float wv = W2s[c * 48 + d] * v_w[d * 48 + e];
#pragma unroll
            for (int t = 0; t < 9; ++t)
                acc[t] = fmaf(wv, v_dw[d * 9 + t], acc[t]);
        }
#pragma unroll
        for (int t = 0; t < 9; ++t)
            cb[(size_t)(t * 64 + c) * 48 + e] = f2bf(acc[t]);
    }
    // pad slots 48..63 -> zero (9*16*48 = 6912 elems)
    for (int i = tid; i < 6912; i += 256) {
        const int e = i % 48;
        const int cp = 48 + ((i / 48) & 15);
        const int t = i / 768;
        cb[(size_t)(t * 64 + cp) * 48 + e] = 0;
    }
}

// ---------------------------------------------------------------------------
// K3: out = cw (*) fea1, 32x8 tile, 256 thr (4 waves = m(2) x g(2)).
//  R13 form + setprio around MFMA cluster.
// ---------------------------------------------------------------------------
__global__ __launch_bounds__(256, 2) void conv3x3_out_kernel(
    const float* __restrict__ fea1, const unsigned short* __restrict__ cwb,
    float* __restrict__ out) {
    __shared__ __align__(16) unsigned short xs[HP2][XSP];

    const int tid = threadIdx.x;
    const int b = blockIdx.y;
    const int tile = xcd_map(blockIdx.x, NTILE);
    const int tx = tile & 7, ty = tile >> 3;
    const float* fb = fea1 + (size_t)b * 48 * HW;
    const unsigned short* cb = cwb + (size_t)b * 27648;

#pragma unroll 1
    for (int i = tid; i < 2 * HP2; i += 256) {
        const int hp = i >> 1, half = i & 1;
        const int hx = hp % HAW, hy = hp / HAW;
        const int gx = tx * TW + hx - 1, gy = ty * TH + hy - 1;
        const bool inb = ((unsigned)gx < (unsigned)IMG) && ((unsigned)gy < (unsigned)IMG);
        const int pix = inb ? (gy * IMG + gx) : 0;
        const int ch0 = half * 24;
        unsigned int w[12];
#pragma unroll
        for (int c = 0; c < 12; ++c) {
            const float lo = inb ? fb[(size_t)(ch0 + 2 * c) * HW + pix] : 0.f;
            const float hi = inb ? fb[(size_t)(ch0 + 2 * c + 1) * HW + pix] : 0.f;
            w[c] = (unsigned)f2bf(lo) | ((unsigned)f2bf(hi) << 16);
        }
#pragma unroll
        for (int c = 0; c < 12; ++c)
            *(unsigned int*)&xs[hp][ch0 + 2 * c] = w[c];
    }
    __syncthreads();

    const int wave = tid >> 6, lane = tid & 63;
    const int l31 = lane & 31, lhi = lane >> 5;
    const int m = wave & 1, g = wave >> 1;

    f32x16 C[4];
#pragma unroll
    for (int nf = 0; nf < 4; ++nf)
#pragma unroll
        for (int r = 0; r < 16; ++r) C[nf][r] = 0.f;

#pragma unroll 1
    for (int ks = 0; ks < 3; ++ks) {
        bf16x8 Bc[6][3];
#pragma unroll
        for (int rr = 0; rr < 6; ++rr)
#pragma unroll
            for (int dd = 0; dd < 3; ++dd)
                Bc[rr][dd] = *(const bf16x8*)&xs[(4 * g + rr) * HAW + l31 + dd][ks * 16 + lhi * 8];
        bf16x8 Af[9];
#pragma unroll
        for (int tap = 0; tap < 9; ++tap)
            Af[tap] = *(const bf16x8*)&cb[((size_t)tap * 64 + m * 32 + l31) * 48 + ks * 16 + lhi * 8];
        __builtin_amdgcn_s_setprio(1);
#pragma unroll
        for (int tap = 0; tap < 9; ++tap) {
            const int dy = tap / 3, dx = tap % 3;
#pragma unroll
            for (int nf = 0; nf < 4; ++nf)
                C[nf] = __builtin_amdgcn_mfma_f32_32x32x16_bf16(Af[tap], Bc[nf + dy][dx], C[nf], 0, 0, 0);
        }
        __builtin_amdgcn_s_setprio(0);
    }

    float* ob = out + (size_t)b * 48 * HW;
#pragma unroll
    for (int nf = 0; nf < 4; ++nf) {
        const int gpx = (ty * TH + 4 * g + nf) * IMG + tx * TW + l31;
#pragma unroll
        for (int r = 0; r < 16; ++r) {
            const int och = m * 32 + (r & 3) + 8 * (r >> 2) + 4 * lhi;
            if (m == 0 || r < 8) ob[(size_t)och * HW + gpx] = C[nf][r];
        }
    }
}

// ---------------------------------------------------------------------------
extern "C" void kernel_launch(void* const* d_in, const int* in_sizes, int n_in,
                              void* d_out, int out_size, void* d_ws, size_t ws_size,
                              hipStream_t stream) {
    const float* fea0 = (const float*)d_in[0];
    const float* fea1 = (const float*)d_in[1];
    const float* qk_w = (const float*)d_in[2];
    const float* qk_dw = (const float*)d_in[3];
    const float* v_w = (const float*)d_in[4];
    const float* v_dw = (const float*)d_in[5];
    const float* proj_w = (const float*)d_in[6];
    const float* temperature = (const float*)d_in[7];
    float* out = (float*)d_out;

    char* ws = (char*)d_ws;
    float* stats = (float*)ws;                                     // 6144 B
    unsigned short* cwb = (unsigned short*)(ws + 8192);            // 221184 B
    unsigned short* qcwb = (unsigned short*)(ws + 8192 + 221184);  // 110592 B

    hipMemsetAsync(stats, 0, (size_t)NB * 384 * sizeof(float), stream);

    prep_qcw_kernel<<<216, 256, 0, stream>>>(qk_w, qk_dw, qcwb);
    fused_qk_stats_kernel<<<dim3(NTILE, NB), 512, 0, stream>>>(fea0, qcwb, stats);
    softmax_w2_cw_kernel<<<NB, 256, 0, stream>>>(stats, proj_w, temperature, v_w, v_dw, cwb);
    conv3x3_out_kernel<<<dim3(NTILE, NB), 256, 0, stream>>>(fea1, cwb, out);
}

// Round 18
// 108.488 us; speedup vs baseline: 1.2050x; 1.2050x over previous
//
#include <hip/hip_runtime.h>
#include <cstddef>

#define IMG 256
#define HW 65536
#define NB 4
#define NHEADS 8
#define TW 32
#define TH 8
#define HAW 34
#define HAH 10
#define HP2 (HAW*HAH)   // 340
#define NTILE 256       // (256/32)*(256/8)
#define XSP 56          // xs pitch in ushorts (112 B, 16B-aligned)

typedef short bf16x8 __attribute__((ext_vector_type(8)));
typedef float f32x4 __attribute__((ext_vector_type(4)));
typedef float f32x16 __attribute__((ext_vector_type(16)));

__device__ __forceinline__ unsigned short f2bf(float f) {
    unsigned int x = __float_as_uint(f);
    unsigned int r = (x + 0x7fffu + ((x >> 16) & 1u)) >> 16;
    return (unsigned short)r;
}

// bijective XCD-contiguous remap (m204)
__device__ __forceinline__ int xcd_map(int bid, int nwg) {
    const int q = nwg >> 3, r = nwg & 7;
    const int x = bid & 7, i = bid >> 3;
    return (x < r ? x * (q + 1) : r * (q + 1) + (x - r) * q) + i;
}

// ---------------------------------------------------------------------------
// K0: combined qk 3x3 weights, layout [tap][slot128][48ch]
// ---------------------------------------------------------------------------
__global__ __launch_bounds__(256) void prep_qcw_kernel(
    const float* __restrict__ qk_w, const float* __restrict__ qk_dw,
    unsigned short* __restrict__ qcwb) {
    const int idx = blockIdx.x * 256 + threadIdx.x;   // 9*128*48 = 55296 exact
    const int e = idx % 48;
    const int slot = (idx / 48) & 127;
    const int tap = idx / (48 * 128);
    const int head = slot >> 4, sub = slot & 15;
    float v = 0.f;
    if (sub < 12) {
        const int row = (sub < 6) ? (head * 6 + sub) : (48 + head * 6 + (sub - 6));
        v = qk_dw[row * 9 + tap] * qk_w[row * 48 + e];
    }
    qcwb[idx] = f2bf(v);
}

// ---------------------------------------------------------------------------
// K1: qk conv + stats. 32x8 tile, 512 thr (8 waves = mp(4) x g(2)).
//  EXACT R13 structure — measured best (52.5 us, VGPR 64+64AGPR = the
//  128-reg/4-waves-per-SIMD knife edge). Ledger of failed variants:
//   - reg double-buffer (R5), B-reg-cache pin (R12), setprio (R16): any
//     scheduling constraint in the ks loop -> +28 VGPR -> occupancy halved.
//   - 512->256-thr blocks (R15), LDS shrink (R14): occupancy is REG-capped,
//     not slot/LDS-capped. min=4 bounds (R8/R9): spill cliffs.
//  Compiler-sunk loads at 4 waves/SIMD is the stable optimum.
// stats per b (384 f32): [0..47]=qq(h*6+c), [48..95]=kk, [96..]=h*36+cc*6+d
// LDS: 38080 + 18432 + 1536 = 58048 B
// ---------------------------------------------------------------------------
__global__ __launch_bounds__(512, 2) void fused_qk_stats_kernel(
    const float* __restrict__ fea0, const unsigned short* __restrict__ qcwb,
    float* __restrict__ stats) {
    __shared__ __align__(16) unsigned short xs[HP2][XSP];   // 38080 B
    __shared__ __align__(16) unsigned short sg[8][16][72];  // 18432 B
    __shared__ float sacc[384];

    const int tid = threadIdx.x;
    const int b = blockIdx.y;
    const int tile = xcd_map(blockIdx.x, NTILE);
    const int tx = tile & 7, ty = tile >> 3;
    const float* fb = fea0 + (size_t)b * 48 * HW;

    for (int i = tid; i < 384; i += 512) sacc[i] = 0.f;

    // ---- stage 34x10 halo, 48 ch, bf16 (2 threads per px) ----
#pragma unroll 1
    for (int i = tid; i < 2 * HP2; i += 512) {
        const int hp = i >> 1, half = i & 1;
        const int hx = hp % HAW, hy = hp / HAW;
        const int gx = tx * TW + hx - 1, gy = ty * TH + hy - 1;
        const bool inb = ((unsigned)gx < (unsigned)IMG) && ((unsigned)gy < (unsigned)IMG);
        const int pix = inb ? (gy * IMG + gx) : 0;
        const int ch0 = half * 24;
        unsigned int w[12];
#pragma unroll
        for (int c = 0; c < 12; ++c) {
            const float lo = inb ? fb[(size_t)(ch0 + 2 * c) * HW + pix] : 0.f;
            const float hi = inb ? fb[(size_t)(ch0 + 2 * c + 1) * HW + pix] : 0.f;
            w[c] = (unsigned)f2bf(lo) | ((unsigned)f2bf(hi) << 16);
        }
#pragma unroll
        for (int c = 0; c < 12; ++c)
            *(unsigned int*)&xs[hp][ch0 + 2 * c] = w[c];
    }
    __syncthreads();

    const int wave = tid >> 6, lane = tid & 63;
    const int l31 = lane & 31, lhi = lane >> 5;
    const int mp = wave >> 1, g = wave & 1;

    f32x16 C[4];
#pragma unroll
    for (int nf = 0; nf < 4; ++nf)
#pragma unroll
        for (int r = 0; r < 16; ++r) C[nf][r] = 0.f;

#pragma unroll 1
    for (int ks = 0; ks < 3; ++ks) {
        // 18 deduped B fragments: halo rows 4g..4g+5, dx shifts 0..2
        bf16x8 Bc[6][3];
#pragma unroll
        for (int rr = 0; rr < 6; ++rr)
#pragma unroll
            for (int dd = 0; dd < 3; ++dd)
                Bc[rr][dd] = *(const bf16x8*)&xs[(4 * g + rr) * HAW + l31 + dd][ks * 16 + lhi * 8];
        // 9 A fragments for this ks
        bf16x8 Af[9];
#pragma unroll
        for (int tap = 0; tap < 9; ++tap)
            Af[tap] = *(const bf16x8*)&qcwb[((size_t)tap * 128 + mp * 32 + l31) * 48 + ks * 16 + lhi * 8];
#pragma unroll
        for (int tap = 0; tap < 9; ++tap) {
            const int dy = tap / 3, dx = tap % 3;
#pragma unroll
            for (int nf = 0; nf < 4; ++nf)
                C[nf] = __builtin_amdgcn_mfma_f32_32x32x16_bf16(Af[tap], Bc[nf + dy][dx], C[nf], 0, 0, 0);
        }
    }

    // ---- stats: no barrier needed (sg[wave] is wave-private) ----
    const int fr = lane & 15, fg = lane >> 4;
    f32x4 gacc[2];
#pragma unroll
    for (int hh = 0; hh < 2; ++hh)
#pragma unroll
        for (int r = 0; r < 4; ++r) gacc[hh][r] = 0.f;

#pragma unroll
    for (int pair = 0; pair < 2; ++pair) {     // px groups: (C0,C1), (C2,C3)
#pragma unroll
        for (int hh = 0; hh < 2; ++hh) {       // head within mp-pair
#pragma unroll
            for (int rq = 0; rq < 2; ++rq) {
                if (!(rq && lhi)) {
#pragma unroll
                    for (int j = 0; j < 4; ++j) {
                        const int sub = j + 8 * rq + 4 * lhi;
                        sg[wave][sub][l31] = f2bf(C[pair * 2][hh * 8 + rq * 4 + j]);
                        sg[wave][sub][32 + l31] = f2bf(C[pair * 2 + 1][hh * 8 + rq * 4 + j]);
                    }
                }
            }
            asm volatile("s_waitcnt lgkmcnt(0)" ::: "memory");
            __builtin_amdgcn_sched_barrier(0);
            const bf16x8 a0 = *(const bf16x8*)&sg[wave][fr][fg * 8];
            const bf16x8 a1 = *(const bf16x8*)&sg[wave][fr][32 + fg * 8];
            asm volatile("s_waitcnt lgkmcnt(0)" ::: "memory");
            __builtin_amdgcn_sched_barrier(0);
            gacc[hh] = __builtin_amdgcn_mfma_f32_16x16x32_bf16(a0, a0, gacc[hh], 0, 0, 0);
            gacc[hh] = __builtin_amdgcn_mfma_f32_16x16x32_bf16(a1, a1, gacc[hh], 0, 0, 0);
        }
    }

    // ---- emit once per head ----
#pragma unroll
    for (int hh = 0; hh < 2; ++hh) {
        const int h = mp * 2 + hh;
#pragma unroll
        for (int r = 0; r < 4; ++r) {
            const int crow = fg * 4 + r;
            const float vv = gacc[hh][r];
            if (crow < 6) {
                if (fr == crow) atomicAdd(&sacc[h * 6 + crow], vv);
                else if (fr >= 6 && fr < 12)
                    atomicAdd(&sacc[96 + h * 36 + crow * 6 + (fr - 6)], vv);
            } else if (crow < 12 && fr == crow) {
                atomicAdd(&sacc[48 + h * 6 + (crow - 6)], vv);
            }
        }
    }

    __syncthreads();
    for (int i = tid; i < 384; i += 512) atomicAdd(&stats[b * 384 + i], sacc[i]);
}

// ---------------------------------------------------------------------------
// K2: softmax(6) -> W2 = proj . blockdiag(attn) -> combined v-side weights
//  cwb layout [tap][slot64][48] (slots 48..63 zero), bf16.
// ---------------------------------------------------------------------------
__global__ __launch_bounds__(256) void softmax_w2_cw_kernel(
    const float* __restrict__ stats, const float* __restrict__ proj_w,
    const float* __restrict__ temperature, const float* __restrict__ v_w,
    const float* __restrict__ v_dw, unsigned short* __restrict__ cwb) {
    const int b = blockIdx.x;
    const int tid = threadIdx.x;
    __shared__ float attn[NHEADS * 36];
    __shared__ float W2s[48 * 48];
    const float* sb = stats + b * 384;

    if (tid < 48) {
        const int h = tid / 6, cc = tid % 6;
        float nq = fmaxf(sqrtf(sb[tid]), 1e-12f);
        const float tmp = temperature[h];
        float lo[6];
#pragma unroll
        for (int d = 0; d < 6; ++d) {
            const float nk = fmaxf(sqrtf(sb[48 + h * 6 + d]), 1e-12f);
            lo[d] = sb[96 + h * 36 + cc * 6 + d] / (nq * nk) * tmp;
        }
        float m = lo[0];
#pragma unroll
        for (int d = 1; d < 6; ++d) m = fmaxf(m, lo[d]);
        float s = 0.f;
#pragma unroll
        for (int d = 0; d < 6; ++d) { lo[d] = expf(lo[d] - m); s += lo[d]; }
        const float inv = 1.f / s;
#pragma unroll
        for (int d = 0; d < 6; ++d) attn[h * 36 + cc * 6 + d] = lo[d] * inv;
    }
    __syncthreads();

    for (int idx = tid; idx < 48 * 48; idx += 256) {
        const int c = idx / 48, dg = idx % 48;
        const int h = dg / 6, hd = dg % 6;
        float s = 0.f;
#pragma unroll
        for (int cc = 0; cc < 6; ++cc)
            s = fmaf(proj_w[c * 48 + h * 6 + cc], attn[h * 36 + cc * 6 + hd], s);
        W2s[idx] = s;
    }
    __syncthreads();

    unsigned short* cb = cwb + (size_t)b * 27648;
    for (int pp = 0; pp < 9; ++pp) {
        const int pair = pp * 256 + tid;
        const int c = pair / 48, e = pair % 48;
        float acc[9];
#pragma unroll
        for (int t = 0; t < 9; ++t) acc[t] = 0.f;
        for (int d = 0; d < 48; ++d) {
            const float wv = W2s[c * 48 + d] * v_w[d * 48 + e];
#pragma unroll
            for (int t = 0; t < 9; ++t)
                acc[t] = fmaf(wv, v_dw[d * 9 + t], acc[t]);
        }
#pragma unroll
        for (int t = 0; t < 9; ++t)
            cb[(size_t)(t * 64 + c) * 48 + e] = f2bf(acc[t]);
    }
    // pad slots 48..63 -> zero (9*16*48 = 6912 elems)
    for (int i = tid; i < 6912; i += 256) {
        const int e = i % 48;
        const int cp = 48 + ((i / 48) & 15);
        const int t = i / 768;
        cb[(size_t)(t * 64 + cp) * 48 + e] = 0;
    }
}

// ---------------------------------------------------------------------------
// K3: out = cw (*) fea1, 32x8 tile, 256 thr (4 waves = m(2) x g(2)).
//  Exact R13 form (measured best; pins/setprio regress via regalloc).
// ---------------------------------------------------------------------------
__global__ __launch_bounds__(256, 2) void conv3x3_out_kernel(
    const float* __restrict__ fea1, const unsigned short* __restrict__ cwb,
    float* __restrict__ out) {
    __shared__ __align__(16) unsigned short xs[HP2][XSP];

    const int tid = threadIdx.x;
    const int b = blockIdx.y;
    const int tile = xcd_map(blockIdx.x, NTILE);
    const int tx = tile & 7, ty = tile >> 3;
    const float* fb = fea1 + (size_t)b * 48 * HW;
    const unsigned short* cb = cwb + (size_t)b * 27648;

#pragma unroll 1
    for (int i = tid; i < 2 * HP2; i += 256) {
        const int hp = i >> 1, half = i & 1;
        const int hx = hp % HAW, hy = hp / HAW;
        const int gx = tx * TW + hx - 1, gy = ty * TH + hy - 1;
        const bool inb = ((unsigned)gx < (unsigned)IMG) && ((unsigned)gy < (unsigned)IMG);
        const int pix = inb ? (gy * IMG + gx) : 0;
        const int ch0 = half * 24;
        unsigned int w[12];
#pragma unroll
        for (int c = 0; c < 12; ++c) {
            const float lo = inb ? fb[(size_t)(ch0 + 2 * c) * HW + pix] : 0.f;
            const float hi = inb ? fb[(size_t)(ch0 + 2 * c + 1) * HW + pix] : 0.f;
            w[c] = (unsigned)f2bf(lo) | ((unsigned)f2bf(hi) << 16);
        }
#pragma unroll
        for (int c = 0; c < 12; ++c)
            *(unsigned int*)&xs[hp][ch0 + 2 * c] = w[c];
    }
    __syncthreads();

    const int wave = tid >> 6, lane = tid & 63;
    const int l31 = lane & 31, lhi = lane >> 5;
    const int m = wave & 1, g = wave >> 1;

    f32x16 C[4];
#pragma unroll
    for (int nf = 0; nf < 4; ++nf)
#pragma unroll
        for (int r = 0; r < 16; ++r) C[nf][r] = 0.f;

#pragma unroll 1
    for (int ks = 0; ks < 3; ++ks) {
        bf16x8 Bc[6][3];
#pragma unroll
        for (int rr = 0; rr < 6; ++rr)
#pragma unroll
            for (int dd = 0; dd < 3; ++dd)
                Bc[rr][dd] = *(const bf16x8*)&xs[(4 * g + rr) * HAW + l31 + dd][ks * 16 + lhi * 8];
        bf16x8 Af[9];
#pragma unroll
        for (int tap = 0; tap < 9; ++tap)
            Af[tap] = *(const bf16x8*)&cb[((size_t)tap * 64 + m * 32 + l31) * 48 + ks * 16 + lhi * 8];
#pragma unroll
        for (int tap = 0; tap < 9; ++tap) {
            const int dy = tap / 3, dx = tap % 3;
#pragma unroll
            for (int nf = 0; nf < 4; ++nf)
                C[nf] = __builtin_amdgcn_mfma_f32_32x32x16_bf16(Af[tap], Bc[nf + dy][dx], C[nf], 0, 0, 0);
        }
    }

    float* ob = out + (size_t)b * 48 * HW;
#pragma unroll
    for (int nf = 0; nf < 4; ++nf) {
        const int gpx = (ty * TH + 4 * g + nf) * IMG + tx * TW + l31;
#pragma unroll
        for (int r = 0; r < 16; ++r) {
            const int och = m * 32 + (r & 3) + 8 * (r >> 2) + 4 * lhi;
            if (m == 0 || r < 8) ob[(size_t)och * HW + gpx] = C[nf][r];
        }
    }
}

// ---------------------------------------------------------------------------
extern "C" void kernel_launch(void* const* d_in, const int* in_sizes, int n_in,
                              void* d_out, int out_size, void* d_ws, size_t ws_size,
                              hipStream_t stream) {
    const float* fea0 = (const float*)d_in[0];
    const float* fea1 = (const float*)d_in[1];
    const float* qk_w = (const float*)d_in[2];
    const float* qk_dw = (const float*)d_in[3];
    const float* v_w = (const float*)d_in[4];
    const float* v_dw = (const float*)d_in[5];
    const float* proj_w = (const float*)d_in[6];
    const float* temperature = (const float*)d_in[7];
    float* out = (float*)d_out;

    char* ws = (char*)d_ws;
    float* stats = (float*)ws;                                     // 6144 B
    unsigned short* cwb = (unsigned short*)(ws + 8192);            // 221184 B
    unsigned short* qcwb = (unsigned short*)(ws + 8192 + 221184);  // 110592 B

    hipMemsetAsync(stats, 0, (size_t)NB * 384 * sizeof(float), stream);

    prep_qcw_kernel<<<216, 256, 0, stream>>>(qk_w, qk_dw, qcwb);
    fused_qk_stats_kernel<<<dim3(NTILE, NB), 512, 0, stream>>>(fea0, qcwb, stats);
    softmax_w2_cw_kernel<<<NB, 256, 0, stream>>>(stats, proj_w, temperature, v_w, v_dw, cwb);
    conv3x3_out_kernel<<<dim3(NTILE, NB), 256, 0, stream>>>(fea1, cwb, out);
}